// Round 1
// baseline (556.295 us; speedup 1.0000x reference)
//
#include <hip/hip_runtime.h>

typedef unsigned short u16;
typedef unsigned int u32;
typedef short bf16x8 __attribute__((ext_vector_type(8)));
typedef float f32x4 __attribute__((ext_vector_type(4)));

#define B_ 2
#define L_ 2048
#define H_ 16
#define KV_ 4
#define D_ 128
#define HID_ 2048

__device__ __forceinline__ u16 f2bf(float f) {
  union { float f; u32 u; } v; v.f = f;
  u32 u = v.u;
  return (u16)((u + 0x7FFFu + ((u >> 16) & 1u)) >> 16);
}
__device__ __forceinline__ float bf2f(u16 h) {
  union { u32 u; float f; } v; v.u = ((u32)h) << 16;
  return v.f;
}
__device__ __forceinline__ void gl_lds16(const void* g, void* l) {
  __builtin_amdgcn_global_load_lds((__attribute__((address_space(1))) void*)(g),
                                   (__attribute__((address_space(3))) void*)(l),
                                   16, 0, 0);
}

// ---------------- fp32 -> bf16 plain convert (vectorized x4) ----------------
__global__ void k_f2b(const float* __restrict__ src, u16* __restrict__ dst, int n4) {
  int i = blockIdx.x * 256 + threadIdx.x;
  if (i >= n4) return;
  float4 v = ((const float4*)src)[i];
  u32 a = (u32)f2bf(v.x) | ((u32)f2bf(v.y) << 16);
  u32 b = (u32)f2bf(v.z) | ((u32)f2bf(v.w) << 16);
  ((uint2*)dst)[i] = make_uint2(a, b);
}

// ---------------- fp32 (RxC) -> bf16 transposed (CxR) ----------------
__global__ void k_tconv(const float* __restrict__ src, u16* __restrict__ dst,
                        int R, int C) {
  __shared__ float t[32][33];
  int c0 = blockIdx.x * 32, r0 = blockIdx.y * 32;
  for (int i = threadIdx.y; i < 32; i += 8)
    t[i][threadIdx.x] = src[(size_t)(r0 + i) * C + c0 + threadIdx.x];
  __syncthreads();
  for (int i = threadIdx.y; i < 32; i += 8)
    dst[(size_t)(c0 + i) * R + r0 + threadIdx.x] = f2bf(t[threadIdx.x][i]);
}

// ---------------- bf16 GEMM: C(MxN) = A(MxK) @ Bt(NxK)^T ----------------
// 128x128 tile, BK=64, 4 waves (2x2), 4x4 16x16x32 frags per wave (m97 structure)
template <int OUT_BF16>
__global__ __launch_bounds__(256, 2) void k_gemm_bt(
    const u16* __restrict__ A, const u16* __restrict__ Bt, void* __restrict__ Cv,
    int M, int N, int K) {
  __shared__ u16 As[128 * 64];
  __shared__ u16 Bs[128 * 64];
  const int tid = threadIdx.x;
  const int wave = tid >> 6, lane = tid & 63;
  const int wr = wave >> 1, wc = wave & 1;
  const int m0 = blockIdx.y * 128, n0 = blockIdx.x * 128;
  f32x4 acc[4][4];
  for (int i = 0; i < 4; ++i)
    for (int j = 0; j < 4; ++j)
      for (int r = 0; r < 4; ++r) acc[i][j][r] = 0.0f;

  const int lrow = lane >> 3;         // 0..7
  const int lcol = (lane & 7) * 8;    // element col of 16B chunk
  const int fm = lane & 15, fk = (lane >> 4) * 8;

  for (int kt = 0; kt < K; kt += 64) {
    for (int p = 0; p < 4; ++p) {
      int roff = wave * 32 + p * 8 + lrow;  // 0..127
      gl_lds16(A + (size_t)(m0 + roff) * K + kt + lcol,
               As + wave * 2048 + p * 512 + lane * 8);
      gl_lds16(Bt + (size_t)(n0 + roff) * K + kt + lcol,
               Bs + wave * 2048 + p * 512 + lane * 8);
    }
    __syncthreads();
    for (int s = 0; s < 2; ++s) {
      bf16x8 af[4], bfr[4];
      for (int i = 0; i < 4; ++i)
        af[i] = *(const bf16x8*)(As + (wr * 64 + i * 16 + fm) * 64 + s * 32 + fk);
      for (int j = 0; j < 4; ++j)
        bfr[j] = *(const bf16x8*)(Bs + (wc * 64 + j * 16 + fm) * 64 + s * 32 + fk);
      for (int i = 0; i < 4; ++i)
        for (int j = 0; j < 4; ++j)
          acc[i][j] = __builtin_amdgcn_mfma_f32_16x16x32_bf16(af[i], bfr[j],
                                                              acc[i][j], 0, 0, 0);
    }
    __syncthreads();
  }
  // epilogue: C/D layout col=lane&15, row=(lane>>4)*4+reg  [m89-verified]
  const int rbase = (lane >> 4) * 4;
  for (int i = 0; i < 4; ++i)
    for (int j = 0; j < 4; ++j) {
      int col = n0 + wc * 64 + j * 16 + fm;
      for (int r = 0; r < 4; ++r) {
        int row = m0 + wr * 64 + i * 16 + rbase + r;
        if (OUT_BF16)
          ((u16*)Cv)[(size_t)row * N + col] = f2bf(acc[i][j][r]);
        else
          ((float*)Cv)[(size_t)row * N + col] = acc[i][j][r];
      }
    }
}

// ---------------- RMSnorm + RoPE + layout shuffle ----------------
// qkv (B*L, 3072) bf16: cols [0,2048)=q heads, [2048,2560)=k heads, [2560,3072)=v
// writes Qb (B,H,L,D), Kb (B,KV,L,D), Vtb (B,KV,D,L), all bf16
__global__ __launch_bounds__(256) void k_norm_rope(
    const u16* __restrict__ qkv, const float* __restrict__ cosp,
    const float* __restrict__ sinp, const float* __restrict__ qw,
    const float* __restrict__ kw, u16* __restrict__ Qb, u16* __restrict__ Kb,
    u16* __restrict__ Vtb) {
  int wid = blockIdx.x * 4 + (threadIdx.x >> 6);
  int lane = threadIdx.x & 63;
  int tok = wid / 24, unit = wid % 24;  // 4096 tokens x 24 units
  int b = tok >> 11, l = tok & 2047;
  const u16* row = qkv + (size_t)tok * 3072;
  int d0 = lane * 2;
  if (unit < 20) {
    // q head (unit<16) or k head (16..19)
    int isq = unit < 16;
    int col = isq ? unit * 128 : 2048 + (unit - 16) * 128;
    u32 u = *(const u32*)(row + col + d0);
    float x0 = bf2f((u16)(u & 0xffff)), x1 = bf2f((u16)(u >> 16));
    float ss = x0 * x0 + x1 * x1;
    for (int m = 1; m < 64; m <<= 1) ss += __shfl_xor(ss, m);
    float rr = rsqrtf(ss * (1.0f / 128.0f) + 1e-6f);
    const float* wv = isq ? qw : kw;
    float n0 = x0 * rr * wv[d0], n1 = x1 * rr * wv[d0 + 1];
    // rotate_half: partner at lane^32, negate for d<64
    float p0 = __shfl_xor(n0, 32), p1 = __shfl_xor(n1, 32);
    float sgn = (lane < 32) ? -1.0f : 1.0f;
    const float* cb = cosp + (size_t)tok * 128;
    const float* sb = sinp + (size_t)tok * 128;
    float o0 = n0 * cb[d0] + sgn * p0 * sb[d0];
    float o1 = n1 * cb[d0 + 1] + sgn * p1 * sb[d0 + 1];
    u32 packed = (u32)f2bf(o0) | ((u32)f2bf(o1) << 16);
    if (isq) {
      size_t off = (((size_t)(b * H_ + unit)) * L_ + l) * D_ + d0;
      *(u32*)(Qb + off) = packed;
    } else {
      size_t off = (((size_t)(b * KV_ + (unit - 16))) * L_ + l) * D_ + d0;
      *(u32*)(Kb + off) = packed;
    }
  } else {
    // v: transpose-copy to (B,KV,D,L)
    int g = unit - 20;
    u16 u0 = row[2560 + g * 128 + d0], u1 = row[2560 + g * 128 + d0 + 1];
    size_t base = (((size_t)(b * KV_ + g)) * D_ + d0) * L_ + l;
    Vtb[base] = u0;
    Vtb[base + L_] = u1;
  }
}

// ---------------- flash attention ----------------
// block = (qt, b*H+h): 64 q rows (4 waves x 16), iterate 32 key tiles of 64
__global__ __launch_bounds__(256, 2) void k_attn(const u16* __restrict__ Qb,
                                                 const u16* __restrict__ Kb,
                                                 const u16* __restrict__ Vtb,
                                                 u16* __restrict__ AO) {
  __shared__ u16 Qs[64 * 128];
  __shared__ u16 Ks[64 * 128];
  __shared__ u16 Vs[128 * 64];
  __shared__ u16 Ps[4 * 16 * 64];  // wave-private P tiles
  const int tid = threadIdx.x, wave = tid >> 6, lane = tid & 63;
  const int qt = blockIdx.x, bh = blockIdx.y;
  const int b = bh >> 4, h = bh & 15, g = h >> 2;
  const u16* Qg = Qb + ((size_t)bh * L_ + qt * 64) * D_;
  const u16* Kg = Kb + ((size_t)(b * KV_ + g)) * L_ * D_;
  const u16* Vg = Vtb + ((size_t)(b * KV_ + g)) * D_ * L_;

  // stage Q once (16KB contiguous)
  for (int p = 0; p < 4; ++p)
    gl_lds16(Qg + wave * 2048 + p * 512 + lane * 8,
             Qs + wave * 2048 + p * 512 + lane * 8);

  f32x4 o[8];
  for (int f = 0; f < 8; ++f)
    for (int r = 0; r < 4; ++r) o[f][r] = 0.0f;
  float mrun[4], lrun[4];
  for (int r = 0; r < 4; ++r) { mrun[r] = -3.0e38f; lrun[r] = 0.0f; }

  const int fm = lane & 15, fk = (lane >> 4) * 8;
  const float scale = 0.08838834764831845f;
  bf16x8 qf[4];

  for (int kt = 0; kt < 32; ++kt) {
    __syncthreads();  // previous tile's LDS reads done
    for (int p = 0; p < 4; ++p) {
      gl_lds16(Kg + kt * 64 * 128 + wave * 2048 + p * 512 + lane * 8,
               Ks + wave * 2048 + p * 512 + lane * 8);
      int e = wave * 2048 + p * 512 + lane * 8;  // Vs elem offset
      gl_lds16(Vg + (size_t)(e >> 6) * L_ + kt * 64 + (e & 63), Vs + e);
    }
    __syncthreads();  // staging landed (barrier drains vmcnt)
    if (kt == 0)
      for (int ks = 0; ks < 4; ++ks)
        qf[ks] = *(const bf16x8*)(Qs + (wave * 16 + fm) * 128 + ks * 32 + fk);

    // S = Q K^T for this wave's 16 rows x 64 keys
    f32x4 s[4];
    for (int n = 0; n < 4; ++n)
      for (int r = 0; r < 4; ++r) s[n][r] = 0.0f;
    for (int ks = 0; ks < 4; ++ks)
      for (int n = 0; n < 4; ++n) {
        bf16x8 kf = *(const bf16x8*)(Ks + (n * 16 + fm) * 128 + ks * 32 + fk);
        s[n] = __builtin_amdgcn_mfma_f32_16x16x32_bf16(qf[ks], kf, s[n], 0, 0, 0);
      }
    for (int n = 0; n < 4; ++n) s[n] *= scale;

    // online softmax (rows live in (lane>>4)*4+r; cols across low-4 lane bits)
    for (int r = 0; r < 4; ++r) {
      float pm = fmaxf(fmaxf(s[0][r], s[1][r]), fmaxf(s[2][r], s[3][r]));
      for (int msk = 1; msk < 16; msk <<= 1) pm = fmaxf(pm, __shfl_xor(pm, msk));
      float mn = fmaxf(mrun[r], pm);
      float al = __expf(mrun[r] - mn);
      mrun[r] = mn;
      float rs = 0.0f;
      for (int n = 0; n < 4; ++n) {
        float p = __expf(s[n][r] - mn);
        rs += p;
        Ps[wave * 1024 + (((lane >> 4) << 2) + r) * 64 + n * 16 + fm] = f2bf(p);
      }
      for (int msk = 1; msk < 16; msk <<= 1) rs += __shfl_xor(rs, msk);
      lrun[r] = lrun[r] * al + rs;
      for (int f = 0; f < 8; ++f) o[f][r] *= al;
    }
    __syncthreads();  // Ps visible (safe ordering before A-frag reads)

    // O += P V
    for (int ks = 0; ks < 2; ++ks) {
      bf16x8 pf = *(const bf16x8*)(Ps + wave * 1024 + fm * 64 + ks * 32 + fk);
      for (int f = 0; f < 8; ++f) {
        bf16x8 vf = *(const bf16x8*)(Vs + (f * 16 + fm) * 64 + ks * 32 + fk);
        o[f] = __builtin_amdgcn_mfma_f32_16x16x32_bf16(pf, vf, o[f], 0, 0, 0);
      }
    }
  }

  // epilogue: AO[b*L + row][h*128 + d] bf16
  size_t ob = ((size_t)(b * L_ + qt * 64 + wave * 16 + ((lane >> 4) << 2))) *
                  (H_ * D_) +
              h * D_ + fm;
  for (int r = 0; r < 4; ++r) {
    float inv = 1.0f / lrun[r];
    for (int f = 0; f < 8; ++f)
      AO[ob + (size_t)r * (H_ * D_) + f * 16] = f2bf(o[f][r] * inv);
  }
}

// ---------------- launcher ----------------
extern "C" void kernel_launch(void* const* d_in, const int* in_sizes, int n_in,
                              void* d_out, int out_size, void* d_ws,
                              size_t ws_size, hipStream_t stream) {
  const float* hidden = (const float*)d_in[0];
  const float* cosp = (const float*)d_in[1];
  const float* sinp = (const float*)d_in[2];
  const float* Wq = (const float*)d_in[3];
  const float* Wk = (const float*)d_in[4];
  const float* Wv = (const float*)d_in[5];
  const float* Wo = (const float*)d_in[6];
  const float* qw = (const float*)d_in[7];
  const float* kw = (const float*)d_in[8];
  float* out = (float*)d_out;

  char* w = (char*)d_ws;
  u16* Xb = (u16*)(w);                          // 4096x2048 bf16, 16MB
  u16* Wtqkv = (u16*)(w + (16u << 20));         // 3072x2048 bf16, 12MB
  u16* Wto = (u16*)(w + (28u << 20));           // 2048x2048 bf16, 8MB
  u16* qkv = (u16*)(w + (36u << 20));           // 4096x3072 bf16, 24MB
  u16* Qb = (u16*)(w + (60u << 20));            // 16MB
  u16* Kb = (u16*)(w + (76u << 20));            // 4MB
  u16* Vtb = (u16*)(w + (80u << 20));           // 4MB (ends at 84MB)
  u16* AO = Xb;                                 // reuse Xb region after GEMM1

  // converts
  k_f2b<<<8192, 256, 0, stream>>>(hidden, Xb, 2097152);
  k_tconv<<<dim3(64, 64), dim3(32, 8), 0, stream>>>(Wq, Wtqkv, 2048, 2048);
  k_tconv<<<dim3(16, 64), dim3(32, 8), 0, stream>>>(Wk, Wtqkv + 2048 * 2048, 2048, 512);
  k_tconv<<<dim3(16, 64), dim3(32, 8), 0, stream>>>(Wv, Wtqkv + 2560 * 2048, 2048, 512);
  k_tconv<<<dim3(64, 64), dim3(32, 8), 0, stream>>>(Wo, Wto, 2048, 2048);
  // qkv projection: (4096x2048) @ (2048x3072)
  k_gemm_bt<1><<<dim3(24, 32), 256, 0, stream>>>(Xb, Wtqkv, qkv, 4096, 3072, 2048);
  // rmsnorm + rope + layout
  k_norm_rope<<<24576, 256, 0, stream>>>(qkv, cosp, sinp, qw, kw, Qb, Kb, Vtb);
  // attention
  k_attn<<<dim3(32, 32), 256, 0, stream>>>(Qb, Kb, Vtb, AO);
  // output projection -> fp32 d_out
  k_gemm_bt<0><<<dim3(16, 32), 256, 0, stream>>>(AO, Wto, out, 4096, 2048, 2048);
}

// Round 3
// 399.081 us; speedup vs baseline: 1.3939x; 1.3939x over previous
//
#include <hip/hip_runtime.h>

typedef unsigned short u16;
typedef unsigned int u32;
typedef short bf16x8 __attribute__((ext_vector_type(8)));
typedef float f32x4 __attribute__((ext_vector_type(4)));
typedef _Float16 f16x4 __attribute__((ext_vector_type(4)));

#define B_ 2
#define L_ 2048
#define H_ 16
#define KV_ 4
#define D_ 128
#define HID_ 2048

// 1/sqrt(128) * log2(e): folded into Q so softmax runs in exp2 domain
#define QSCALE (0.08838834764831845f * 1.4426950408889634f)

__device__ __forceinline__ u16 f2bf(float f) {
  union { float f; u32 u; } v; v.f = f;
  u32 u = v.u;
  return (u16)((u + 0x7FFFu + ((u >> 16) & 1u)) >> 16);
}
__device__ __forceinline__ float bf2f(u16 h) {
  union { u32 u; float f; } v; v.u = ((u32)h) << 16;
  return v.f;
}
__device__ __forceinline__ void gl_lds16(const void* g, void* l) {
  __builtin_amdgcn_global_load_lds((__attribute__((address_space(1))) void*)(g),
                                   (__attribute__((address_space(3))) void*)(l),
                                   16, 0, 0);
}

// ---------------- fp32 -> bf16 plain convert (vectorized x4) ----------------
__global__ void k_f2b(const float* __restrict__ src, u16* __restrict__ dst, int n4) {
  int i = blockIdx.x * 256 + threadIdx.x;
  if (i >= n4) return;
  float4 v = ((const float4*)src)[i];
  u32 a = (u32)f2bf(v.x) | ((u32)f2bf(v.y) << 16);
  u32 b = (u32)f2bf(v.z) | ((u32)f2bf(v.w) << 16);
  ((uint2*)dst)[i] = make_uint2(a, b);
}

// ---------------- fp32 (RxC) -> bf16 transposed (CxR) ----------------
__global__ void k_tconv(const float* __restrict__ src, u16* __restrict__ dst,
                        int R, int C) {
  __shared__ float t[32][33];
  int c0 = blockIdx.x * 32, r0 = blockIdx.y * 32;
  for (int i = threadIdx.y; i < 32; i += 8)
    t[i][threadIdx.x] = src[(size_t)(r0 + i) * C + c0 + threadIdx.x];
  __syncthreads();
  for (int i = threadIdx.y; i < 32; i += 8)
    dst[(size_t)(c0 + i) * R + r0 + threadIdx.x] = f2bf(t[threadIdx.x][i]);
}

// ---------------- bf16 GEMM: C(MxN) = A(MxK) @ Bt(NxK)^T ----------------
template <int OUT_BF16>
__global__ __launch_bounds__(256, 2) void k_gemm_bt(
    const u16* __restrict__ A, const u16* __restrict__ Bt, void* __restrict__ Cv,
    int M, int N, int K) {
  __shared__ u16 As[128 * 64];
  __shared__ u16 Bs[128 * 64];
  const int tid = threadIdx.x;
  const int wave = tid >> 6, lane = tid & 63;
  const int wr = wave >> 1, wc = wave & 1;
  const int m0 = blockIdx.y * 128, n0 = blockIdx.x * 128;
  f32x4 acc[4][4];
  for (int i = 0; i < 4; ++i)
    for (int j = 0; j < 4; ++j)
      for (int r = 0; r < 4; ++r) acc[i][j][r] = 0.0f;

  const int lrow = lane >> 3;
  const int lcol = (lane & 7) * 8;
  const int fm = lane & 15, fk = (lane >> 4) * 8;

  for (int kt = 0; kt < K; kt += 64) {
    for (int p = 0; p < 4; ++p) {
      int roff = wave * 32 + p * 8 + lrow;
      gl_lds16(A + (size_t)(m0 + roff) * K + kt + lcol,
               As + wave * 2048 + p * 512 + lane * 8);
      gl_lds16(Bt + (size_t)(n0 + roff) * K + kt + lcol,
               Bs + wave * 2048 + p * 512 + lane * 8);
    }
    __syncthreads();
    for (int s = 0; s < 2; ++s) {
      bf16x8 af[4], bfr[4];
      for (int i = 0; i < 4; ++i)
        af[i] = *(const bf16x8*)(As + (wr * 64 + i * 16 + fm) * 64 + s * 32 + fk);
      for (int j = 0; j < 4; ++j)
        bfr[j] = *(const bf16x8*)(Bs + (wc * 64 + j * 16 + fm) * 64 + s * 32 + fk);
      for (int i = 0; i < 4; ++i)
        for (int j = 0; j < 4; ++j)
          acc[i][j] = __builtin_amdgcn_mfma_f32_16x16x32_bf16(af[i], bfr[j],
                                                              acc[i][j], 0, 0, 0);
    }
    __syncthreads();
  }
  const int rbase = (lane >> 4) * 4;
  for (int i = 0; i < 4; ++i)
    for (int j = 0; j < 4; ++j) {
      int col = n0 + wc * 64 + j * 16 + fm;
      for (int r = 0; r < 4; ++r) {
        int row = m0 + wr * 64 + i * 16 + rbase + r;
        if (OUT_BF16)
          ((u16*)Cv)[(size_t)row * N + col] = f2bf(acc[i][j][r]);
        else
          ((float*)Cv)[(size_t)row * N + col] = acc[i][j][r];
      }
    }
}

// ---------------- RMSnorm + RoPE + layout shuffle ----------------
// q gets 1/sqrt(D)*log2e folded in; V stored as f16 (for the f16 PV MFMA)
__global__ __launch_bounds__(256) void k_norm_rope(
    const u16* __restrict__ qkv, const float* __restrict__ cosp,
    const float* __restrict__ sinp, const float* __restrict__ qw,
    const float* __restrict__ kw, u16* __restrict__ Qb, u16* __restrict__ Kb,
    u16* __restrict__ Vtb) {
  int wid = blockIdx.x * 4 + (threadIdx.x >> 6);
  int lane = threadIdx.x & 63;
  int tok = wid / 24, unit = wid % 24;
  int b = tok >> 11, l = tok & 2047;
  const u16* row = qkv + (size_t)tok * 3072;
  int d0 = lane * 2;
  if (unit < 20) {
    int isq = unit < 16;
    int col = isq ? unit * 128 : 2048 + (unit - 16) * 128;
    u32 u = *(const u32*)(row + col + d0);
    float x0 = bf2f((u16)(u & 0xffff)), x1 = bf2f((u16)(u >> 16));
    float ss = x0 * x0 + x1 * x1;
    for (int m = 1; m < 64; m <<= 1) ss += __shfl_xor(ss, m);
    float rr = rsqrtf(ss * (1.0f / 128.0f) + 1e-6f);
    const float* wv = isq ? qw : kw;
    float n0 = x0 * rr * wv[d0], n1 = x1 * rr * wv[d0 + 1];
    float p0 = __shfl_xor(n0, 32), p1 = __shfl_xor(n1, 32);
    float sgn = (lane < 32) ? -1.0f : 1.0f;
    const float* cb = cosp + (size_t)tok * 128;
    const float* sb = sinp + (size_t)tok * 128;
    float o0 = n0 * cb[d0] + sgn * p0 * sb[d0];
    float o1 = n1 * cb[d0 + 1] + sgn * p1 * sb[d0 + 1];
    if (isq) {
      o0 *= QSCALE;
      o1 *= QSCALE;
      u32 packed = (u32)f2bf(o0) | ((u32)f2bf(o1) << 16);
      size_t off = (((size_t)(b * H_ + unit)) * L_ + l) * D_ + d0;
      *(u32*)(Qb + off) = packed;
    } else {
      u32 packed = (u32)f2bf(o0) | ((u32)f2bf(o1) << 16);
      size_t off = (((size_t)(b * KV_ + (unit - 16))) * L_ + l) * D_ + d0;
      *(u32*)(Kb + off) = packed;
    }
  } else {
    // v: transpose to (B,KV,D,L), convert to f16
    int g = unit - 20;
    float v0 = bf2f(row[2560 + g * 128 + d0]);
    float v1 = bf2f(row[2560 + g * 128 + d0 + 1]);
    union { _Float16 h; u16 u; } c0, c1;
    c0.h = (_Float16)v0;
    c1.h = (_Float16)v1;
    size_t base = (((size_t)(b * KV_ + g)) * D_ + d0) * L_ + l;
    Vtb[base] = c0.u;
    Vtb[base + L_] = c1.u;
  }
}

// ---------------- flash attention (S^T formulation) ----------------
// S^T = K Q^T  (C-frags: col=q, rows=keys)  ->  softmax mostly lane-local
// P^T C-frag IS the B-frag of mfma_f32_16x16x16f16  ->  O^T = V^T P^T, no LDS for P
// K/V LDS tiles XOR-swizzled via the global source address of global_load_lds
__global__ __launch_bounds__(256, 4) void k_attn(const u16* __restrict__ Qb,
                                                 const u16* __restrict__ Kb,
                                                 const u16* __restrict__ Vtb,
                                                 u16* __restrict__ AO) {
  __shared__ u16 smem[16384];  // Ks = smem[0:8192] (64x128), Vs = smem[8192:] (128x64 f16)
  u16* Ks = smem;
  u16* Vs = smem + 8192;
  const int tid = threadIdx.x, wave = tid >> 6, lane = tid & 63;
  const int quad = lane >> 4, fm = lane & 15;
  const int f7 = fm & 7;
  const int qt = blockIdx.x, bh = blockIdx.y;
  const int b = bh >> 4, h = bh & 15, g = h >> 2;
  const u16* Kg = Kb + ((size_t)(b * KV_ + g)) * L_ * D_;
  const u16* Vg = Vtb + ((size_t)(b * KV_ + g)) * D_ * L_;

  // Q B-frags straight from global: q = qt*64 + wave*16 + fm, d = ks*32+quad*8+{0..7}
  const u16* Qg = Qb + ((size_t)bh * L_ + qt * 64 + wave * 16 + fm) * D_;
  bf16x8 qf[4];
  for (int ks = 0; ks < 4; ++ks)
    qf[ks] = *(const bf16x8*)(Qg + ks * 32 + quad * 8);

  f32x4 o[8];
  for (int f = 0; f < 8; ++f)
    for (int r = 0; r < 4; ++r) o[f][r] = 0.0f;
  float mrun = -1.0e30f, lrun = 0.0f;

  // staging geometry (computed once)
  const int eK = wave * 2048 + (lane << 3);     // + p*512
  const int cK = lane & 15;                      // K chunk slot
  const int cV = lane & 7;                       // V chunk slot
  for (int kt = 0; kt < 32; ++kt) {
    __syncthreads();  // previous tile's LDS reads done
    for (int p = 0; p < 4; ++p) {
      int e = eK + p * 512;
      // K tile: 64 rows x 128 u16; swizzle 16B chunks by row&7
      int rowK = e >> 7;
      int gK = (cK & 8) | ((cK & 7) ^ (rowK & 7));
      gl_lds16(Kg + (size_t)(kt * 64 + rowK) * 128 + gK * 8, Ks + e);
      // V tile: 128 rows(d) x 64 u16(keys) f16; swizzle 16B chunks by row&7
      int rowV = e >> 6;
      int gV = cV ^ (rowV & 7);
      gl_lds16(Vg + (size_t)rowV * L_ + kt * 64 + gV * 8, Vs + e);
    }
    __syncthreads();

    // S^T = K Q^T : frags n over key ranges, rows=keys, col=q
    f32x4 s[4];
    for (int n = 0; n < 4; ++n)
      for (int r = 0; r < 4; ++r) s[n][r] = 0.0f;
    for (int ks = 0; ks < 4; ++ks) {
      int c = 4 * ks + quad;
      int cp = (c & 8) | ((c & 7) ^ f7);
      for (int n = 0; n < 4; ++n) {
        bf16x8 kf = *(const bf16x8*)(Ks + (n * 16 + fm) * 128 + cp * 8);
        s[n] = __builtin_amdgcn_mfma_f32_16x16x32_bf16(kf, qf[ks], s[n], 0, 0, 0);
      }
    }

    // online softmax: lane holds 16 keys for its q; cross-quad = 2 shuffles
    f32x4 m4 = s[0];
    for (int n = 1; n < 4; ++n)
      for (int r = 0; r < 4; ++r) m4[r] = fmaxf(m4[r], s[n][r]);
    float pm = fmaxf(fmaxf(m4[0], m4[1]), fmaxf(m4[2], m4[3]));
    pm = fmaxf(pm, __shfl_xor(pm, 16));
    pm = fmaxf(pm, __shfl_xor(pm, 32));
    float mn = fmaxf(mrun, pm);
    float al = __builtin_amdgcn_exp2f(mrun - mn);
    mrun = mn;
    float rs = 0.0f;
    f16x4 pf[4];
    for (int n = 0; n < 4; ++n) {
      float p0 = __builtin_amdgcn_exp2f(s[n][0] - mn);
      float p1 = __builtin_amdgcn_exp2f(s[n][1] - mn);
      float p2 = __builtin_amdgcn_exp2f(s[n][2] - mn);
      float p3 = __builtin_amdgcn_exp2f(s[n][3] - mn);
      rs += (p0 + p1) + (p2 + p3);
      pf[n][0] = (_Float16)p0;
      pf[n][1] = (_Float16)p1;
      pf[n][2] = (_Float16)p2;
      pf[n][3] = (_Float16)p3;
    }
    rs += __shfl_xor(rs, 16);
    rs += __shfl_xor(rs, 32);
    lrun = lrun * al + rs;
    if (__any(al != 1.0f))
      for (int f = 0; f < 8; ++f)
        for (int r = 0; r < 4; ++r) o[f][r] *= al;

    // O^T += V^T P^T : A = V-frag (d rows, key k), B = pf[n] (P^T C-frag directly)
    for (int n = 0; n < 4; ++n) {
      int cl = 2 * n + (quad >> 1);
      int off = (cl ^ f7) * 8 + (quad & 1) * 4;  // elem offset in V row
      for (int f = 0; f < 8; ++f) {
        f16x4 vf = *(const f16x4*)(Vs + (f * 16 + fm) * 64 + off);
        o[f] = __builtin_amdgcn_mfma_f32_16x16x16f16(vf, pf[n], o[f], 0, 0, 0);
      }
    }
  }

  // epilogue: O^T (lane: col q=wave*16+fm, rows d=f*16+quad*4+r) -> LDS (pitch 136) -> coalesced AO
  __syncthreads();
  float inv = 1.0f / lrun;
  const int qrow = wave * 16 + fm;
  for (int f = 0; f < 8; ++f) {
    u32 w01 = (u32)f2bf(o[f][0] * inv) | ((u32)f2bf(o[f][1] * inv) << 16);
    u32 w23 = (u32)f2bf(o[f][2] * inv) | ((u32)f2bf(o[f][3] * inv) << 16);
    int e = qrow * 136 + f * 16 + quad * 4;
    *(u32*)(smem + e) = w01;
    *(u32*)(smem + e + 2) = w23;
  }
  __syncthreads();
  const size_t tok0 = (size_t)b * L_ + qt * 64;
  for (int it = 0; it < 8; ++it) {
    int rrow = wave * 16 + it * 2 + (lane >> 5);
    int cc = (lane & 31) * 4;
    uint2 v = *(const uint2*)(smem + rrow * 136 + cc);
    *(uint2*)(AO + (tok0 + rrow) * (H_ * D_) + h * D_ + cc) = v;
  }
}

// ---------------- launcher ----------------
extern "C" void kernel_launch(void* const* d_in, const int* in_sizes, int n_in,
                              void* d_out, int out_size, void* d_ws,
                              size_t ws_size, hipStream_t stream) {
  const float* hidden = (const float*)d_in[0];
  const float* cosp = (const float*)d_in[1];
  const float* sinp = (const float*)d_in[2];
  const float* Wq = (const float*)d_in[3];
  const float* Wk = (const float*)d_in[4];
  const float* Wv = (const float*)d_in[5];
  const float* Wo = (const float*)d_in[6];
  const float* qw = (const float*)d_in[7];
  const float* kw = (const float*)d_in[8];
  float* out = (float*)d_out;

  char* w = (char*)d_ws;
  u16* Xb = (u16*)(w);                          // 4096x2048 bf16, 16MB
  u16* Wtqkv = (u16*)(w + (16u << 20));         // 3072x2048 bf16, 12MB
  u16* Wto = (u16*)(w + (28u << 20));           // 2048x2048 bf16, 8MB
  u16* qkv = (u16*)(w + (36u << 20));           // 4096x3072 bf16, 24MB
  u16* Qb = (u16*)(w + (60u << 20));            // 16MB
  u16* Kb = (u16*)(w + (76u << 20));            // 4MB
  u16* Vtb = (u16*)(w + (80u << 20));           // 4MB f16 (ends 84MB)
  u16* AO = Xb;                                 // reuse after GEMM1

  k_f2b<<<8192, 256, 0, stream>>>(hidden, Xb, 2097152);
  k_tconv<<<dim3(64, 64), dim3(32, 8), 0, stream>>>(Wq, Wtqkv, 2048, 2048);
  k_tconv<<<dim3(16, 64), dim3(32, 8), 0, stream>>>(Wk, Wtqkv + 2048 * 2048, 2048, 512);
  k_tconv<<<dim3(16, 64), dim3(32, 8), 0, stream>>>(Wv, Wtqkv + 2560 * 2048, 2048, 512);
  k_tconv<<<dim3(64, 64), dim3(32, 8), 0, stream>>>(Wo, Wto, 2048, 2048);
  k_gemm_bt<1><<<dim3(24, 32), 256, 0, stream>>>(Xb, Wtqkv, qkv, 4096, 3072, 2048);
  k_norm_rope<<<24576, 256, 0, stream>>>(qkv, cosp, sinp, qw, kw, Qb, Kb, Vtb);
  k_attn<<<dim3(32, 32), 256, 0, stream>>>(Qb, Kb, Vtb, AO);
  k_gemm_bt<0><<<dim3(16, 32), 256, 0, stream>>>(AO, Wto, out, 4096, 2048, 2048);
}